// Round 11
// baseline (154.415 us; speedup 1.0000x reference)
//
#include <hip/hip_runtime.h>
#include <hip/hip_bf16.h>

// MyConv1d_ell_2_sequential: B=16384, C=128, O=128, LIN=18, out (B,128,54) fp32.
// out[b,o,t*6+l] = sum over tap instances (j, i, coef) of coef * sum_c x[b,c,i]*Fj[c,o]
// R2: LDS-transpose epilogue -> coalesced float4 stores (286 -> 188 us).
// R5: + filter pre-pack to MFMA B-frags in d_ws (188 -> 145 us).
// R6: lgkm-only epilogue barriers: NEUTRAL. R8: lockstep interleave: WORSE (177).
// R10: zero-barrier per-wave epilogue (145 -> 141.8).
// R11: persistent 2-tile blocks (grid 512): t1's staging loads issued during
//      t0's epilogue store stream (issue at k%4==0, consume at k%4==2, 2 iters
//      = ~2 store rounds of latency hiding; pend[8] in regs). Removes the
//      serial stage phase of every 2nd tile + halves per-block fixed costs.
//      1 block/CU (210 regs/wave) => phases serialize per CU; this overlaps them.

using short8 = short __attribute__((ext_vector_type(8)));
using f32x4  = float __attribute__((ext_vector_type(4)));

#define DEVINL __device__ __forceinline__

DEVINL unsigned short f2bf(float f) {
    unsigned int u = __float_as_uint(f);
    unsigned int r = u + 0x7FFFu + ((u >> 16) & 1u);   // RNE
    return (unsigned short)(r >> 16);
}

// instance tables: per i (0..14), list of (acc slot, filter plane j)
__constant__ constexpr int START[16] = {0,6,12,18,23,31,37,46,54,63,69,77,82,88,94,100};
__constant__ constexpr int SLOT[100] = {
 0,1,2,3,3,4,
 1,2,3,4,4,5,
 6,7,8,9,9,10,
 7,8,9,10,10,
 0,11,12,13,2,14,14,3,
 12,1,13,14,3,4,
 15,6,16,1,17,8,9,3,4,
 16,7,17,2,9,10,4,5,
 18,11,19,7,13,2,14,9,10,
 19,12,8,14,3,10,
 20,15,12,17,8,14,3,3,
 16,13,9,4,4,
 18,16,13,9,9,4,
 19,17,14,10,10,5,
 20,19,17,14,14,10
};
__constant__ constexpr int JJ[100] = {
 0,0,2,2,2,2,
 0,0,2,2,2,2,
 0,0,2,2,2,2,
 0,0,2,2,2,
 1,0,0,2,3,2,2,3,
 0,1,0,2,3,3,
 0,1,0,1,2,3,3,3,3,
 0,1,0,1,3,3,3,3,
 0,1,0,1,3,4,3,3,3,
 0,1,1,3,4,3,
 0,1,1,3,4,3,4,4,
 1,1,4,4,4,
 1,1,4,4,4,4,
 1,1,4,4,4,4,
 1,1,4,4,4,4
};
// slot -> u (column in 0..53); remaining 33 columns are structural zeros
__constant__ constexpr int UCOL[21] = {0,1,2,3,4,5,6,7,8,9,10,12,13,14,15,18,19,20,24,25,30};

// ---- pre-kernel: pack filters into MFMA B-fragments (bf16, pre-scaled) ----
// bp layout: [wid(8)][j(5)][q(4)][lane(64)] x short8  (160 KB total)
__global__ __launch_bounds__(256)
void pack_filters(const float* __restrict__ f2, const float* __restrict__ f3,
                  unsigned short* __restrict__ bp)
{
    int p = blockIdx.x * 256 + threadIdx.x;       // 0..10239
    if (p >= 10240) return;
    int L   = p & 63;
    int t   = p >> 6;                             // wid*20 + j*4 + q
    int q   = t & 3;
    int j   = (t >> 2) % 5;
    int wid = t / 20;
    int o   = wid * 16 + (L & 15);
    int c0  = q * 32 + (L >> 4) * 8;
    float scale = (j < 2) ? 0.0625f : 0.051031036307982884f;
    unsigned short v[8];
    #pragma unroll
    for (int e = 0; e < 8; ++e) {
        int c = c0 + e;
        float f = (j < 2) ? f2[(o * 128 + c) * 2 + j]
                          : f3[(o * 128 + c) * 3 + (j - 2)];
        v[e] = f2bf(f * scale);
    }
    *reinterpret_cast<short8*>(bp + (long)p * 8) = *reinterpret_cast<const short8*>(v);
}

__global__ __launch_bounds__(512, 2)
void conv1d_ell_kernel(const float* __restrict__ x,
                       const unsigned short* __restrict__ bpack,
                       float* __restrict__ out)
{
    // xl: x tile bf16 [i(15)][b(16)][c(128)] XOR-swizzled          61440 B
    // ob: 8 per-wave float buffers [m(16)][u(54)] = 8 x 3456 B     27648 B
    __shared__ __align__(16) unsigned char smem[89088];
    unsigned short* xl = reinterpret_cast<unsigned short*>(smem);
    float*          ob = reinterpret_cast<float*>(smem + 61440);

    const int tid  = threadIdx.x;
    const int lane = tid & 63;
    const int wid  = tid >> 6;          // 0..7  -> o tile = wid*16
    const int m    = lane & 15;
    const int kblk = lane >> 4;         // 0..3
    const int g    = lane >> 4;         // D row group

    const long b_base = (long)blockIdx.x * 32;   // t0: rows [+0,+16), t1: [+16,+32)

    // ---- stage t0 -> LDS (fp32 -> bf16, transpose (b,c,i)->(i,b,c)) ----
    #pragma unroll
    for (int q = 0; q < 4; ++q) {
        int r = tid + q * 512;          // 0..2047
        int b = r >> 7;
        int c = r & 127;
        const float* px = x + (b_base + b) * 2304 + (long)c * 18;
        float v[16];
        #pragma unroll
        for (int t = 0; t < 8; ++t) {
            float2 w = reinterpret_cast<const float2*>(px)[t];
            v[2*t] = w.x; v[2*t+1] = w.y;
        }
        #pragma unroll
        for (int i = 0; i < 15; ++i) {
            int idx = (i * 2048 + b * 128 + c) ^ ((b & 7) << 3);
            xl[idx] = f2bf(v[i]);
        }
    }

    // ---- load pre-packed filter B-fragments: 20 coalesced 16B loads ----
    short8 bfrag[5][4];
    {
        const unsigned short* bp = bpack + ((long)(wid * 20) * 64 + lane) * 8;
        #pragma unroll
        for (int j = 0; j < 5; ++j)
            #pragma unroll
            for (int q = 0; q < 4; ++q)
                bfrag[j][q] = *reinterpret_cast<const short8*>(bp + (long)(j * 4 + q) * 64 * 8);
    }

    f32x4 acc[21];
    #pragma unroll
    for (int s = 0; s < 21; ++s) acc[s] = (f32x4){0.f, 0.f, 0.f, 0.f};

    auto compute = [&]() {
        #pragma unroll
        for (int i = 0; i < 15; ++i) {
            short8 a[4];
            #pragma unroll
            for (int q = 0; q < 4; ++q) {
                int c0 = q * 32 + kblk * 8;
                int idx = (i * 2048 + m * 128 + c0) ^ ((m & 7) << 3);
                a[q] = *reinterpret_cast<const short8*>(&xl[idx]);
            }
            #pragma unroll
            for (int n = START[i]; n < START[i + 1]; ++n) {
                const int s = SLOT[n];
                const int j = JJ[n];
                #pragma unroll
                for (int q = 0; q < 4; ++q) {
                    acc[s] = __builtin_amdgcn_mfma_f32_16x16x32_bf16(a[q], bfrag[j][q], acc[s], 0, 0, 0);
                }
            }
        }
    };

    __syncthreads();        // xl(t0) staged by all waves
    compute();              // t0
    __syncthreads();        // all waves done READING xl(t0) -> t1 staging may begin

    // ---- per-wave epilogue buffers ----
    float* wbuf = ob + wid * 864;       // [m(16)][u(54)] private to this wave
    {   // zero-fill once; scatter rewrites the same 21 cols every row
        float4 z = make_float4(0.f, 0.f, 0.f, 0.f);
        #pragma unroll
        for (int t = 0; t < 3; ++t)
            *reinterpret_cast<float4*>(wbuf + 4 * (lane + 64 * t)) = z;
        if (lane < 24)
            *reinterpret_cast<float4*>(wbuf + 4 * (lane + 192)) = z;
    }

    // ---- epilogue t0 + pipelined stage of t1 (no barriers inside) ----
    // q-group q: loads issued at k=4q, consumed (LDS writes) at k=4q+2 -> the
    // HBM latency hides under ~2 rows of the store stream.
    float2 pend[8];
    #pragma unroll
    for (int k = 0; k < 16; ++k) {
        if ((k & 3) == 0) {             // issue loads for q = k>>2
            const int q = k >> 2;
            const int r = tid + q * 512;
            const int b = r >> 7, c = r & 127;
            const float* px = x + (b_base + 16 + b) * 2304 + (long)c * 18;
            #pragma unroll
            for (int t = 0; t < 8; ++t)
                pend[t] = reinterpret_cast<const float2*>(px)[t];
        }
        if ((k & 3) == 2) {             // consume q = k>>2 (issued 2 iters ago)
            const int q = k >> 2;
            const int r = tid + q * 512;
            const int b = r >> 7, c = r & 127;
            #pragma unroll
            for (int t = 0; t < 8; ++t) {
                const int i0 = 2 * t;
                xl[(i0 * 2048 + b * 128 + c) ^ ((b & 7) << 3)] = f2bf(pend[t].x);
                if (i0 + 1 < 15)
                    xl[((i0 + 1) * 2048 + b * 128 + c) ^ ((b & 7) << 3)] = f2bf(pend[t].y);
            }
        }
        if (g == (k >> 2)) {            // 16 lanes scatter row k (static reg idx)
            float* dst = wbuf + m * 54; // word stride 54 -> 16 distinct banks
            #pragma unroll
            for (int s = 0; s < 21; ++s) dst[UCOL[s]] = acc[s][k & 3];
        }
        asm volatile("s_waitcnt lgkmcnt(0)" ::: "memory");
        float* dstg = out + ((b_base + k) * 128 + wid * 16) * 54;
        #pragma unroll
        for (int t = 0; t < 3; ++t) {
            float4 w = *reinterpret_cast<const float4*>(wbuf + 4 * (lane + 64 * t));
            *reinterpret_cast<float4*>(dstg + 4 * (lane + 64 * t)) = w;
        }
        if (lane < 24) {
            float4 w = *reinterpret_cast<const float4*>(wbuf + 4 * (lane + 192));
            *reinterpret_cast<float4*>(dstg + 4 * (lane + 192)) = w;
        }
    }

    __syncthreads();        // xl(t1) staged by all waves; wbuf reads done

    // ---- tile 1: compute + plain epilogue ----
    #pragma unroll
    for (int s = 0; s < 21; ++s) acc[s] = (f32x4){0.f, 0.f, 0.f, 0.f};
    compute();              // t1

    #pragma unroll
    for (int k = 0; k < 16; ++k) {
        if (g == (k >> 2)) {
            float* dst = wbuf + m * 54;
            #pragma unroll
            for (int s = 0; s < 21; ++s) dst[UCOL[s]] = acc[s][k & 3];
        }
        asm volatile("s_waitcnt lgkmcnt(0)" ::: "memory");
        float* dstg = out + ((b_base + 16 + k) * 128 + wid * 16) * 54;
        #pragma unroll
        for (int t = 0; t < 3; ++t) {
            float4 w = *reinterpret_cast<const float4*>(wbuf + 4 * (lane + 64 * t));
            *reinterpret_cast<float4*>(dstg + 4 * (lane + 64 * t)) = w;
        }
        if (lane < 24) {
            float4 w = *reinterpret_cast<const float4*>(wbuf + 4 * (lane + 192));
            *reinterpret_cast<float4*>(dstg + 4 * (lane + 192)) = w;
        }
    }
}

extern "C" void kernel_launch(void* const* d_in, const int* in_sizes, int n_in,
                              void* d_out, int out_size, void* d_ws, size_t ws_size,
                              hipStream_t stream) {
    const float* x   = (const float*)d_in[0];
    const float* sos = (const float*)d_in[1];
    const float* f2  = (const float*)d_in[2];
    const float* f3  = (const float*)d_in[3];
    float* out = (float*)d_out;
    unsigned short* bp = (unsigned short*)d_ws;    // 160 KB of fragments

    pack_filters<<<dim3(40), dim3(256), 0, stream>>>(f2, f3, bp);
    conv1d_ell_kernel<<<dim3(512), dim3(512), 0, stream>>>(x, bp, out);

    // output 1: pass-through copy of sum_of_squares (16384 floats)
    (void)hipMemcpyAsync(out + 113246208LL, sos, 16384 * sizeof(float),
                         hipMemcpyDeviceToDevice, stream);
}

// Round 13
// 137.367 us; speedup vs baseline: 1.1241x; 1.1241x over previous
//
#include <hip/hip_runtime.h>
#include <hip/hip_bf16.h>

// MyConv1d_ell_2_sequential: B=16384, C=128, O=128, LIN=18, out (B,128,54) fp32.
// out[b,o,t*6+l] = sum over tap instances (j, i, coef) of coef * sum_c x[b,c,i]*Fj[c,o]
// R2: LDS-transpose epilogue -> coalesced float4 stores (286 -> 188 us).
// R5: + filter pre-pack to MFMA B-frags in d_ws (188 -> 145 us).
// R6/R8/R11: barrier/overlap experiments -> neutral or worse. R10: per-wave
//     zero-barrier epilogue (141.8). Lesson: manual intra-block overlap loses;
//     1 block/CU (210 regs/wave) serializes stage->compute->store per CU.
// R12: TWO blocks/CU via register+LDS diet, letting the HW overlap block N's
//     store stream with block N+1's stage/compute:
//     (a) q-outermost compute (#pragma unroll 1): bfrag 80 -> 20 regs;
//     (b) epilogue buffer aliased over dead xl: LDS 89 -> 60 KB;
//     (c) __launch_bounds__(512,4): cap 128 regs/wave (acc 84 AGPR + ~40 VGPR).
// R13: resubmit of R12 (container died before benching).

using short8 = short __attribute__((ext_vector_type(8)));
using f32x4  = float __attribute__((ext_vector_type(4)));

#define DEVINL __device__ __forceinline__

DEVINL unsigned short f2bf(float f) {
    unsigned int u = __float_as_uint(f);
    unsigned int r = u + 0x7FFFu + ((u >> 16) & 1u);   // RNE
    return (unsigned short)(r >> 16);
}

// instance tables: per i (0..14), list of (acc slot, filter plane j)
__constant__ constexpr int START[16] = {0,6,12,18,23,31,37,46,54,63,69,77,82,88,94,100};
__constant__ constexpr int SLOT[100] = {
 0,1,2,3,3,4,
 1,2,3,4,4,5,
 6,7,8,9,9,10,
 7,8,9,10,10,
 0,11,12,13,2,14,14,3,
 12,1,13,14,3,4,
 15,6,16,1,17,8,9,3,4,
 16,7,17,2,9,10,4,5,
 18,11,19,7,13,2,14,9,10,
 19,12,8,14,3,10,
 20,15,12,17,8,14,3,3,
 16,13,9,4,4,
 18,16,13,9,9,4,
 19,17,14,10,10,5,
 20,19,17,14,14,10
};
__constant__ constexpr int JJ[100] = {
 0,0,2,2,2,2,
 0,0,2,2,2,2,
 0,0,2,2,2,2,
 0,0,2,2,2,
 1,0,0,2,3,2,2,3,
 0,1,0,2,3,3,
 0,1,0,1,2,3,3,3,3,
 0,1,0,1,3,3,3,3,
 0,1,0,1,3,4,3,3,3,
 0,1,1,3,4,3,
 0,1,1,3,4,3,4,4,
 1,1,4,4,4,
 1,1,4,4,4,4,
 1,1,4,4,4,4,
 1,1,4,4,4,4
};
// slot -> u (column in 0..53); remaining 33 columns are structural zeros
__constant__ constexpr int UCOL[21] = {0,1,2,3,4,5,6,7,8,9,10,12,13,14,15,18,19,20,24,25,30};

// ---- pre-kernel: pack filters into MFMA B-fragments (bf16, pre-scaled) ----
// bp layout: [wid(8)][j(5)][q(4)][lane(64)] x short8  (160 KB total)
__global__ __launch_bounds__(256)
void pack_filters(const float* __restrict__ f2, const float* __restrict__ f3,
                  unsigned short* __restrict__ bp)
{
    int p = blockIdx.x * 256 + threadIdx.x;       // 0..10239
    if (p >= 10240) return;
    int L   = p & 63;
    int t   = p >> 6;                             // wid*20 + j*4 + q
    int q   = t & 3;
    int j   = (t >> 2) % 5;
    int wid = t / 20;
    int o   = wid * 16 + (L & 15);
    int c0  = q * 32 + (L >> 4) * 8;
    float scale = (j < 2) ? 0.0625f : 0.051031036307982884f;
    unsigned short v[8];
    #pragma unroll
    for (int e = 0; e < 8; ++e) {
        int c = c0 + e;
        float f = (j < 2) ? f2[(o * 128 + c) * 2 + j]
                          : f3[(o * 128 + c) * 3 + (j - 2)];
        v[e] = f2bf(f * scale);
    }
    *reinterpret_cast<short8*>(bp + (long)p * 8) = *reinterpret_cast<const short8*>(v);
}

__global__ __launch_bounds__(512, 4)
void conv1d_ell_kernel(const float* __restrict__ x,
                       const unsigned short* __restrict__ bpack,
                       float* __restrict__ out)
{
    // xl: x tile bf16 [i(15)][b(16)][c(128)] XOR-swizzled   61440 B
    // ob: epilogue buffers ALIASED over xl (xl dead then)    27648 B
    __shared__ __align__(16) unsigned char smem[61440];
    unsigned short* xl = reinterpret_cast<unsigned short*>(smem);
    float*          ob = reinterpret_cast<float*>(smem);

    const int tid  = threadIdx.x;
    const int lane = tid & 63;
    const int wid  = tid >> 6;          // 0..7  -> o tile = wid*16
    const int m    = lane & 15;
    const int kblk = lane >> 4;         // 0..3
    const int g    = lane >> 4;         // D row group

    const long b_base = (long)blockIdx.x * 16;

    // ---- stage x -> LDS (fp32 -> bf16, transpose (b,c,i)->(i,b,c)) ----
    #pragma unroll
    for (int q = 0; q < 4; ++q) {
        int r = tid + q * 512;          // 0..2047
        int b = r >> 7;
        int c = r & 127;
        const float* px = x + (b_base + b) * 2304 + (long)c * 18;
        float v[16];
        #pragma unroll
        for (int t = 0; t < 8; ++t) {
            float2 w = reinterpret_cast<const float2*>(px)[t];
            v[2*t] = w.x; v[2*t+1] = w.y;
        }
        #pragma unroll
        for (int i = 0; i < 15; ++i) {
            int idx = (i * 2048 + b * 128 + c) ^ ((b & 7) << 3);
            xl[idx] = f2bf(v[i]);
        }
    }

    f32x4 acc[21];
    #pragma unroll
    for (int s = 0; s < 21; ++s) acc[s] = (f32x4){0.f, 0.f, 0.f, 0.f};

    __syncthreads();

    // ---- compute: q (K-chunk) OUTERMOST, 5 B-frags live at a time ----
    #pragma unroll 1
    for (int q = 0; q < 4; ++q) {
        short8 bq[5];
        const unsigned short* bp = bpack + ((long)((wid * 20 + q) * 64 + lane)) * 8;
        #pragma unroll
        for (int j = 0; j < 5; ++j)
            bq[j] = *reinterpret_cast<const short8*>(bp + (long)(j * 4) * 64 * 8);

        const int c0 = q * 32 + kblk * 8;
        #pragma unroll
        for (int i = 0; i < 15; ++i) {
            int idx = (i * 2048 + m * 128 + c0) ^ ((m & 7) << 3);
            short8 a = *reinterpret_cast<const short8*>(&xl[idx]);
            #pragma unroll
            for (int n = START[i]; n < START[i + 1]; ++n) {
                acc[SLOT[n]] = __builtin_amdgcn_mfma_f32_16x16x32_bf16(a, bq[JJ[n]], acc[SLOT[n]], 0, 0, 0);
            }
        }
    }

    __syncthreads();    // ALL waves done reading xl -> safe to alias ob over it

    // ---- per-wave epilogue (R10): zero barriers, contiguous 3456-B regions ----
    float* wbuf = ob + wid * 864;       // [m(16)][u(54)] private to this wave

    {   // zero-fill once; scatter rewrites the same 21 cols every row
        float4 z = make_float4(0.f, 0.f, 0.f, 0.f);
        #pragma unroll
        for (int t = 0; t < 3; ++t)
            *reinterpret_cast<float4*>(wbuf + 4 * (lane + 64 * t)) = z;
        if (lane < 24)
            *reinterpret_cast<float4*>(wbuf + 4 * (lane + 192)) = z;
    }

    #pragma unroll
    for (int k = 0; k < 16; ++k) {
        if (g == (k >> 2)) {            // 16 lanes scatter row k (static reg idx)
            float* dst = wbuf + m * 54; // word stride 54 -> 16 distinct banks
            #pragma unroll
            for (int s = 0; s < 21; ++s) dst[UCOL[s]] = acc[s][k & 3];
        }
        // compiler fence: keep copy reads after scatter writes (HW is in-order)
        asm volatile("s_waitcnt lgkmcnt(0)" ::: "memory");
        float* dstg = out + ((b_base + k) * 128 + wid * 16) * 54;
        #pragma unroll
        for (int t = 0; t < 3; ++t) {
            float4 w = *reinterpret_cast<const float4*>(wbuf + 4 * (lane + 64 * t));
            *reinterpret_cast<float4*>(dstg + 4 * (lane + 64 * t)) = w;
        }
        if (lane < 24) {
            float4 w = *reinterpret_cast<const float4*>(wbuf + 4 * (lane + 192));
            *reinterpret_cast<float4*>(dstg + 4 * (lane + 192)) = w;
        }
    }
}

extern "C" void kernel_launch(void* const* d_in, const int* in_sizes, int n_in,
                              void* d_out, int out_size, void* d_ws, size_t ws_size,
                              hipStream_t stream) {
    const float* x   = (const float*)d_in[0];
    const float* sos = (const float*)d_in[1];
    const float* f2  = (const float*)d_in[2];
    const float* f3  = (const float*)d_in[3];
    float* out = (float*)d_out;
    unsigned short* bp = (unsigned short*)d_ws;    // 160 KB of fragments

    pack_filters<<<dim3(40), dim3(256), 0, stream>>>(f2, f3, bp);
    conv1d_ell_kernel<<<dim3(1024), dim3(512), 0, stream>>>(x, bp, out);

    // output 1: pass-through copy of sum_of_squares (16384 floats)
    (void)hipMemcpyAsync(out + 113246208LL, sos, 16384 * sizeof(float),
                         hipMemcpyDeviceToDevice, stream);
}

// Round 15
// 117.074 us; speedup vs baseline: 1.3189x; 1.1733x over previous
//
#include <hip/hip_runtime.h>
#include <hip/hip_bf16.h>

// MyConv1d_ell_2_sequential: B=16384, C=128, O=128, LIN=18, out (B,128,54) fp32.
// out[b,o,t*6+l] = sum over tap instances (j, i, coef) of coef * sum_c x[b,c,i]*Fj[c,o]
// R2: LDS-transpose epilogue -> coalesced float4 stores (286 -> 188 us).
// R5: + filter pre-pack to MFMA B-frags in d_ws (188 -> 145 us).
// R10: per-wave zero-barrier epilogue (145 -> 141.8).
// R12/13: 2-blocks/CU diet: q-outermost bfrag (80->20 regs), ob aliased over xl
//     (LDS 60 KB), launch_bounds(512,4) (141.8 -> 137.4).
// R14: epilogue v3: (a) 2-row batched scatter/copy (8 iters, not 16 -> half the
//     lgkm drains, 2x the MLP per burst); (b) nontemporal stores (output is
//     write-once -> evict-first, keep L2 for x/bp); everything else identical.
// R15: fix compile error (nontemporal builtin needs ext_vector type, not
//     HIP_vector_type float4) -- epilogue path now uses f32x4 throughout.

using short8 = short __attribute__((ext_vector_type(8)));
using f32x4  = float __attribute__((ext_vector_type(4)));

#define DEVINL __device__ __forceinline__

DEVINL unsigned short f2bf(float f) {
    unsigned int u = __float_as_uint(f);
    unsigned int r = u + 0x7FFFu + ((u >> 16) & 1u);   // RNE
    return (unsigned short)(r >> 16);
}

// instance tables: per i (0..14), list of (acc slot, filter plane j)
__constant__ constexpr int START[16] = {0,6,12,18,23,31,37,46,54,63,69,77,82,88,94,100};
__constant__ constexpr int SLOT[100] = {
 0,1,2,3,3,4,
 1,2,3,4,4,5,
 6,7,8,9,9,10,
 7,8,9,10,10,
 0,11,12,13,2,14,14,3,
 12,1,13,14,3,4,
 15,6,16,1,17,8,9,3,4,
 16,7,17,2,9,10,4,5,
 18,11,19,7,13,2,14,9,10,
 19,12,8,14,3,10,
 20,15,12,17,8,14,3,3,
 16,13,9,4,4,
 18,16,13,9,9,4,
 19,17,14,10,10,5,
 20,19,17,14,14,10
};
__constant__ constexpr int JJ[100] = {
 0,0,2,2,2,2,
 0,0,2,2,2,2,
 0,0,2,2,2,2,
 0,0,2,2,2,
 1,0,0,2,3,2,2,3,
 0,1,0,2,3,3,
 0,1,0,1,2,3,3,3,3,
 0,1,0,1,3,3,3,3,
 0,1,0,1,3,4,3,3,3,
 0,1,1,3,4,3,
 0,1,1,3,4,3,4,4,
 1,1,4,4,4,
 1,1,4,4,4,4,
 1,1,4,4,4,4,
 1,1,4,4,4,4
};
// slot -> u (column in 0..53); remaining 33 columns are structural zeros
__constant__ constexpr int UCOL[21] = {0,1,2,3,4,5,6,7,8,9,10,12,13,14,15,18,19,20,24,25,30};

// ---- pre-kernel: pack filters into MFMA B-fragments (bf16, pre-scaled) ----
// bp layout: [wid(8)][j(5)][q(4)][lane(64)] x short8  (160 KB total)
__global__ __launch_bounds__(256)
void pack_filters(const float* __restrict__ f2, const float* __restrict__ f3,
                  unsigned short* __restrict__ bp)
{
    int p = blockIdx.x * 256 + threadIdx.x;       // 0..10239
    if (p >= 10240) return;
    int L   = p & 63;
    int t   = p >> 6;                             // wid*20 + j*4 + q
    int q   = t & 3;
    int j   = (t >> 2) % 5;
    int wid = t / 20;
    int o   = wid * 16 + (L & 15);
    int c0  = q * 32 + (L >> 4) * 8;
    float scale = (j < 2) ? 0.0625f : 0.051031036307982884f;
    unsigned short v[8];
    #pragma unroll
    for (int e = 0; e < 8; ++e) {
        int c = c0 + e;
        float f = (j < 2) ? f2[(o * 128 + c) * 2 + j]
                          : f3[(o * 128 + c) * 3 + (j - 2)];
        v[e] = f2bf(f * scale);
    }
    *reinterpret_cast<short8*>(bp + (long)p * 8) = *reinterpret_cast<const short8*>(v);
}

__global__ __launch_bounds__(512, 4)
void conv1d_ell_kernel(const float* __restrict__ x,
                       const unsigned short* __restrict__ bpack,
                       float* __restrict__ out)
{
    // xl: x tile bf16 [i(15)][b(16)][c(128)] XOR-swizzled   61440 B
    // ob: epilogue buffers ALIASED over xl (xl dead then):
    //     8 waves x 2 rows x 864 floats = 55296 B
    __shared__ __align__(16) unsigned char smem[61440];
    unsigned short* xl = reinterpret_cast<unsigned short*>(smem);
    float*          ob = reinterpret_cast<float*>(smem);

    const int tid  = threadIdx.x;
    const int lane = tid & 63;
    const int wid  = tid >> 6;          // 0..7  -> o tile = wid*16
    const int m    = lane & 15;
    const int kblk = lane >> 4;         // 0..3
    const int g    = lane >> 4;         // D row group

    const long b_base = (long)blockIdx.x * 16;

    // ---- stage x -> LDS (fp32 -> bf16, transpose (b,c,i)->(i,b,c)) ----
    #pragma unroll
    for (int q = 0; q < 4; ++q) {
        int r = tid + q * 512;          // 0..2047
        int b = r >> 7;
        int c = r & 127;
        const float* px = x + (b_base + b) * 2304 + (long)c * 18;
        float v[16];
        #pragma unroll
        for (int t = 0; t < 8; ++t) {
            float2 w = reinterpret_cast<const float2*>(px)[t];
            v[2*t] = w.x; v[2*t+1] = w.y;
        }
        #pragma unroll
        for (int i = 0; i < 15; ++i) {
            int idx = (i * 2048 + b * 128 + c) ^ ((b & 7) << 3);
            xl[idx] = f2bf(v[i]);
        }
    }

    f32x4 acc[21];
    #pragma unroll
    for (int s = 0; s < 21; ++s) acc[s] = (f32x4){0.f, 0.f, 0.f, 0.f};

    __syncthreads();

    // ---- compute: q (K-chunk) OUTERMOST, 5 B-frags live at a time ----
    #pragma unroll 1
    for (int q = 0; q < 4; ++q) {
        short8 bq[5];
        const unsigned short* bp = bpack + ((long)((wid * 20 + q) * 64 + lane)) * 8;
        #pragma unroll
        for (int j = 0; j < 5; ++j)
            bq[j] = *reinterpret_cast<const short8*>(bp + (long)(j * 4) * 64 * 8);

        const int c0 = q * 32 + kblk * 8;
        #pragma unroll
        for (int i = 0; i < 15; ++i) {
            int idx = (i * 2048 + m * 128 + c0) ^ ((m & 7) << 3);
            short8 a = *reinterpret_cast<const short8*>(&xl[idx]);
            #pragma unroll
            for (int n = START[i]; n < START[i + 1]; ++n) {
                acc[SLOT[n]] = __builtin_amdgcn_mfma_f32_16x16x32_bf16(a, bq[JJ[n]], acc[SLOT[n]], 0, 0, 0);
            }
        }
    }

    __syncthreads();    // ALL waves done reading xl -> safe to alias ob over it

    // ---- per-wave epilogue v3: 2-row batches, nt stores, zero barriers ----
    float* wbuf = ob + wid * 1728;      // [row(2)][m(16)][u(54)] private buffer

    {   // zero-fill once (432 f32x4); scatter rewrites the same 21 cols/row
        f32x4 z = (f32x4){0.f, 0.f, 0.f, 0.f};
        #pragma unroll
        for (int t = 0; t < 6; ++t)
            *reinterpret_cast<f32x4*>(wbuf + 4 * (lane + 64 * t)) = z;
        if (lane < 48)
            *reinterpret_cast<f32x4*>(wbuf + 4 * (lane + 384)) = z;
    }

    #pragma unroll
    for (int p = 0; p < 8; ++p) {       // rows 2p, 2p+1
        if (g == (p >> 1)) {            // owning 16 lanes scatter both rows
            const int r0 = (p & 1) * 2; // compile-time (loop unrolled)
            float* d0 = wbuf + m * 54;
            float* d1 = wbuf + 864 + m * 54;
            #pragma unroll
            for (int s = 0; s < 21; ++s) d0[UCOL[s]] = acc[s][r0];
            #pragma unroll
            for (int s = 0; s < 21; ++s) d1[UCOL[s]] = acc[s][r0 + 1];
        }
        // compiler fence: keep copy reads after scatter writes (DS is in-order)
        asm volatile("s_waitcnt lgkmcnt(0)" ::: "memory");
        float* dstg = out + ((b_base + 2 * p) * 128 + wid * 16) * 54;
        #pragma unroll
        for (int row = 0; row < 2; ++row) {
            const float* src = wbuf + row * 864;
            float* dst = dstg + row * 6912;
            #pragma unroll
            for (int t = 0; t < 3; ++t) {
                f32x4 w = *reinterpret_cast<const f32x4*>(src + 4 * (lane + 64 * t));
                __builtin_nontemporal_store(w, reinterpret_cast<f32x4*>(dst + 4 * (lane + 64 * t)));
            }
            if (lane < 24) {
                f32x4 w = *reinterpret_cast<const f32x4*>(src + 4 * (lane + 192));
                __builtin_nontemporal_store(w, reinterpret_cast<f32x4*>(dst + 4 * (lane + 192)));
            }
        }
    }
}

extern "C" void kernel_launch(void* const* d_in, const int* in_sizes, int n_in,
                              void* d_out, int out_size, void* d_ws, size_t ws_size,
                              hipStream_t stream) {
    const float* x   = (const float*)d_in[0];
    const float* sos = (const float*)d_in[1];
    const float* f2  = (const float*)d_in[2];
    const float* f3  = (const float*)d_in[3];
    float* out = (float*)d_out;
    unsigned short* bp = (unsigned short*)d_ws;    // 160 KB of fragments

    pack_filters<<<dim3(40), dim3(256), 0, stream>>>(f2, f3, bp);
    conv1d_ell_kernel<<<dim3(1024), dim3(512), 0, stream>>>(x, bp, out);

    // output 1: pass-through copy of sum_of_squares (16384 floats)
    (void)hipMemcpyAsync(out + 113246208LL, sos, 16384 * sizeof(float),
                         hipMemcpyDeviceToDevice, stream);
}

// Round 17
// 115.726 us; speedup vs baseline: 1.3343x; 1.0116x over previous
//
#include <hip/hip_runtime.h>
#include <hip/hip_bf16.h>

// MyConv1d_ell_2_sequential: B=16384, C=128, O=128, LIN=18, out (B,128,54) fp32.
// out[b,o,t*6+l] = sum over tap instances (j, i, coef) of coef * sum_c x[b,c,i]*Fj[c,o]
// R2: LDS-transpose epilogue (286 -> 188). R5: filter pre-pack (188 -> 145).
// R10: per-wave zero-barrier epilogue (-> 141.8). R12/13: 2 blocks/CU diet
// (-> 137.4). R15: 2-row batched epilogue + nontemporal stores (-> 117.1).
// R16: 4 blocks/CU attempt: launch_bounds(512,8) needs <=64 regs/wave, acc alone
//      is 84 -> launch failed (zeros). Occupancy is HARD-CAPPED at 2 blocks/CU
//      (128 regs = 4 waves/SIMD bin); that direction is structurally dead.
// R17: R15 verbatim + sum_of_squares copy folded into the conv kernel (block i
//      owns rows [16i,16i+16) -> tid<16 copies sos[b_base+tid]); drops the
//      hipMemcpyAsync dispatch from the graph.

using short8 = short __attribute__((ext_vector_type(8)));
using f32x4  = float __attribute__((ext_vector_type(4)));

#define DEVINL __device__ __forceinline__

DEVINL unsigned short f2bf(float f) {
    unsigned int u = __float_as_uint(f);
    unsigned int r = u + 0x7FFFu + ((u >> 16) & 1u);   // RNE
    return (unsigned short)(r >> 16);
}

// instance tables: per i (0..14), list of (acc slot, filter plane j)
__constant__ constexpr int START[16] = {0,6,12,18,23,31,37,46,54,63,69,77,82,88,94,100};
__constant__ constexpr int SLOT[100] = {
 0,1,2,3,3,4,
 1,2,3,4,4,5,
 6,7,8,9,9,10,
 7,8,9,10,10,
 0,11,12,13,2,14,14,3,
 12,1,13,14,3,4,
 15,6,16,1,17,8,9,3,4,
 16,7,17,2,9,10,4,5,
 18,11,19,7,13,2,14,9,10,
 19,12,8,14,3,10,
 20,15,12,17,8,14,3,3,
 16,13,9,4,4,
 18,16,13,9,9,4,
 19,17,14,10,10,5,
 20,19,17,14,14,10
};
__constant__ constexpr int JJ[100] = {
 0,0,2,2,2,2,
 0,0,2,2,2,2,
 0,0,2,2,2,2,
 0,0,2,2,2,
 1,0,0,2,3,2,2,3,
 0,1,0,2,3,3,
 0,1,0,1,2,3,3,3,3,
 0,1,0,1,3,3,3,3,
 0,1,0,1,3,4,3,3,3,
 0,1,1,3,4,3,
 0,1,1,3,4,3,4,4,
 1,1,4,4,4,
 1,1,4,4,4,4,
 1,1,4,4,4,4,
 1,1,4,4,4,4
};
// slot -> u (column in 0..53); remaining 33 columns are structural zeros
__constant__ constexpr int UCOL[21] = {0,1,2,3,4,5,6,7,8,9,10,12,13,14,15,18,19,20,24,25,30};

// ---- pre-kernel: pack filters into MFMA B-fragments (bf16, pre-scaled) ----
// bp layout: [wid(8)][j(5)][q(4)][lane(64)] x short8  (160 KB total)
__global__ __launch_bounds__(256)
void pack_filters(const float* __restrict__ f2, const float* __restrict__ f3,
                  unsigned short* __restrict__ bp)
{
    int p = blockIdx.x * 256 + threadIdx.x;       // 0..10239
    if (p >= 10240) return;
    int L   = p & 63;
    int t   = p >> 6;                             // wid*20 + j*4 + q
    int q   = t & 3;
    int j   = (t >> 2) % 5;
    int wid = t / 20;
    int o   = wid * 16 + (L & 15);
    int c0  = q * 32 + (L >> 4) * 8;
    float scale = (j < 2) ? 0.0625f : 0.051031036307982884f;
    unsigned short v[8];
    #pragma unroll
    for (int e = 0; e < 8; ++e) {
        int c = c0 + e;
        float f = (j < 2) ? f2[(o * 128 + c) * 2 + j]
                          : f3[(o * 128 + c) * 3 + (j - 2)];
        v[e] = f2bf(f * scale);
    }
    *reinterpret_cast<short8*>(bp + (long)p * 8) = *reinterpret_cast<const short8*>(v);
}

__global__ __launch_bounds__(512, 4)
void conv1d_ell_kernel(const float* __restrict__ x,
                       const unsigned short* __restrict__ bpack,
                       const float* __restrict__ sos,
                       float* __restrict__ out)
{
    // xl: x tile bf16 [i(15)][b(16)][c(128)] XOR-swizzled   61440 B
    // ob: epilogue buffers ALIASED over xl (xl dead then):
    //     8 waves x 2 rows x 864 floats = 55296 B
    __shared__ __align__(16) unsigned char smem[61440];
    unsigned short* xl = reinterpret_cast<unsigned short*>(smem);
    float*          ob = reinterpret_cast<float*>(smem);

    const int tid  = threadIdx.x;
    const int lane = tid & 63;
    const int wid  = tid >> 6;          // 0..7  -> o tile = wid*16
    const int m    = lane & 15;
    const int kblk = lane >> 4;         // 0..3
    const int g    = lane >> 4;         // D row group

    const long b_base = (long)blockIdx.x * 16;

    // ---- output 1: this block's 16 sum_of_squares values (hidden in staging) ----
    if (tid < 16)
        out[113246208LL + b_base + tid] = sos[b_base + tid];

    // ---- stage x -> LDS (fp32 -> bf16, transpose (b,c,i)->(i,b,c)) ----
    #pragma unroll
    for (int q = 0; q < 4; ++q) {
        int r = tid + q * 512;          // 0..2047
        int b = r >> 7;
        int c = r & 127;
        const float* px = x + (b_base + b) * 2304 + (long)c * 18;
        float v[16];
        #pragma unroll
        for (int t = 0; t < 8; ++t) {
            float2 w = reinterpret_cast<const float2*>(px)[t];
            v[2*t] = w.x; v[2*t+1] = w.y;
        }
        #pragma unroll
        for (int i = 0; i < 15; ++i) {
            int idx = (i * 2048 + b * 128 + c) ^ ((b & 7) << 3);
            xl[idx] = f2bf(v[i]);
        }
    }

    f32x4 acc[21];
    #pragma unroll
    for (int s = 0; s < 21; ++s) acc[s] = (f32x4){0.f, 0.f, 0.f, 0.f};

    __syncthreads();

    // ---- compute: q (K-chunk) OUTERMOST, 5 B-frags live at a time ----
    #pragma unroll 1
    for (int q = 0; q < 4; ++q) {
        short8 bq[5];
        const unsigned short* bp = bpack + ((long)((wid * 20 + q) * 64 + lane)) * 8;
        #pragma unroll
        for (int j = 0; j < 5; ++j)
            bq[j] = *reinterpret_cast<const short8*>(bp + (long)(j * 4) * 64 * 8);

        const int c0 = q * 32 + kblk * 8;
        #pragma unroll
        for (int i = 0; i < 15; ++i) {
            int idx = (i * 2048 + m * 128 + c0) ^ ((m & 7) << 3);
            short8 a = *reinterpret_cast<const short8*>(&xl[idx]);
            #pragma unroll
            for (int n = START[i]; n < START[i + 1]; ++n) {
                acc[SLOT[n]] = __builtin_amdgcn_mfma_f32_16x16x32_bf16(a, bq[JJ[n]], acc[SLOT[n]], 0, 0, 0);
            }
        }
    }

    __syncthreads();    // ALL waves done reading xl -> safe to alias ob over it

    // ---- per-wave epilogue: 2-row batches, nt stores, zero barriers ----
    float* wbuf = ob + wid * 1728;      // [row(2)][m(16)][u(54)] private buffer

    {   // zero-fill once (432 f32x4); scatter rewrites the same 21 cols/row
        f32x4 z = (f32x4){0.f, 0.f, 0.f, 0.f};
        #pragma unroll
        for (int t = 0; t < 6; ++t)
            *reinterpret_cast<f32x4*>(wbuf + 4 * (lane + 64 * t)) = z;
        if (lane < 48)
            *reinterpret_cast<f32x4*>(wbuf + 4 * (lane + 384)) = z;
    }

    #pragma unroll
    for (int p = 0; p < 8; ++p) {       // rows 2p, 2p+1
        if (g == (p >> 1)) {            // owning 16 lanes scatter both rows
            const int r0 = (p & 1) * 2; // compile-time (loop unrolled)
            float* d0 = wbuf + m * 54;
            float* d1 = wbuf + 864 + m * 54;
            #pragma unroll
            for (int s = 0; s < 21; ++s) d0[UCOL[s]] = acc[s][r0];
            #pragma unroll
            for (int s = 0; s < 21; ++s) d1[UCOL[s]] = acc[s][r0 + 1];
        }
        // compiler fence: keep copy reads after scatter writes (DS is in-order)
        asm volatile("s_waitcnt lgkmcnt(0)" ::: "memory");
        float* dstg = out + ((b_base + 2 * p) * 128 + wid * 16) * 54;
        #pragma unroll
        for (int row = 0; row < 2; ++row) {
            const float* src = wbuf + row * 864;
            float* dst = dstg + row * 6912;
            #pragma unroll
            for (int t = 0; t < 3; ++t) {
                f32x4 w = *reinterpret_cast<const f32x4*>(src + 4 * (lane + 64 * t));
                __builtin_nontemporal_store(w, reinterpret_cast<f32x4*>(dst + 4 * (lane + 64 * t)));
            }
            if (lane < 24) {
                f32x4 w = *reinterpret_cast<const f32x4*>(src + 4 * (lane + 192));
                __builtin_nontemporal_store(w, reinterpret_cast<f32x4*>(dst + 4 * (lane + 192)));
            }
        }
    }
}

extern "C" void kernel_launch(void* const* d_in, const int* in_sizes, int n_in,
                              void* d_out, int out_size, void* d_ws, size_t ws_size,
                              hipStream_t stream) {
    const float* x   = (const float*)d_in[0];
    const float* sos = (const float*)d_in[1];
    const float* f2  = (const float*)d_in[2];
    const float* f3  = (const float*)d_in[3];
    float* out = (float*)d_out;
    unsigned short* bp = (unsigned short*)d_ws;    // 160 KB of fragments

    pack_filters<<<dim3(40), dim3(256), 0, stream>>>(f2, f3, bp);
    conv1d_ell_kernel<<<dim3(1024), dim3(512), 0, stream>>>(x, bp, sos, out);
}